// Round 1
// 2868.515 us; speedup vs baseline: 1.2282x; 1.2282x over previous
//
#include <hip/hip_runtime.h>

#define TLEN 32768
#define NB 4
#define NLAYER 30

typedef short bf16x8 __attribute__((ext_vector_type(8)));
typedef float f32x16 __attribute__((ext_vector_type(16)));
#define MFMA32(a, b, c) __builtin_amdgcn_mfma_f32_32x32x16_bf16(a, b, c, 0, 0, 0)

__device__ __forceinline__ unsigned short bfh(float x) {
  unsigned int u = __float_as_uint(x);
  return (unsigned short)((u + 0x7fffu + ((u >> 16) & 1u)) >> 16);
}
__device__ __forceinline__ void fsplit(float x, unsigned short& h, unsigned short& l) {
  unsigned int u = __float_as_uint(x);
  unsigned int hb = (u + 0x7fffu + ((u >> 16) & 1u)) & 0xffff0000u;
  h = (unsigned short)(hb >> 16);
  l = bfh(x - __uint_as_float(hb));
}
__device__ __forceinline__ float bflo(unsigned int p) { return __uint_as_float(p << 16); }
__device__ __forceinline__ float bfhi2(unsigned int p) { return __uint_as_float(p & 0xffff0000u); }

__device__ __forceinline__ void split4(float4 v, uint2& h, uint2& l) {
  unsigned short h0, l0, h1, l1, h2, l2, h3, l3;
  fsplit(v.x, h0, l0); fsplit(v.y, h1, l1);
  fsplit(v.z, h2, l2); fsplit(v.w, h3, l3);
  h.x = (unsigned int)h0 | ((unsigned int)h1 << 16);
  h.y = (unsigned int)h2 | ((unsigned int)h3 << 16);
  l.x = (unsigned int)l0 | ((unsigned int)l1 << 16);
  l.y = (unsigned int)l2 | ((unsigned int)l3 << 16);
}
__device__ __forceinline__ bf16x8 asb(uint4 v) {
  union { uint4 u; bf16x8 b; } x; x.u = v; return x.b;
}
__device__ __forceinline__ bf16x8 asb2(uint2 a, uint2 b) {
  union { uint4 u; bf16x8 v; } x;
  x.u.x = a.x; x.u.y = a.y; x.u.z = b.x; x.u.w = b.y; return x.v;
}
__device__ __forceinline__ float fast_sigmoid(float x) { return 1.0f / (1.0f + __expf(-x)); }
__device__ __forceinline__ float fast_tanh(float x) { return 1.0f - 2.0f / (1.0f + __expf(2.0f * x)); }

// ---------------- prep ----------------

// chunk-local causal conv: xt[b][ti][r] = cw[r]*y[b][base+ti] + cb[r]
__global__ __launch_bounds__(256) void wn_causal_k(
    const float* __restrict__ y, const float* __restrict__ cw,
    const float* __restrict__ cb, float* __restrict__ xt, int base, int cext) {
  int ti = blockIdx.x * 64 + (threadIdx.x >> 2);
  int cg = (threadIdx.x & 3) << 4;
  int b = blockIdx.y;
  float yv = y[(size_t)b * TLEN + base + ti];
  float* o = xt + ((size_t)b * cext + ti) * 64 + cg;
#pragma unroll
  for (int j = 0; j < 4; ++j) {
    float4 w = *(const float4*)(cw + cg + 4 * j);
    float4 bb = *(const float4*)(cb + cg + 4 * j);
    float4 v; v.x = w.x * yv + bb.x; v.y = w.y * yv + bb.y;
    v.z = w.z * yv + bb.z; v.w = w.w * yv + bb.w;
    *(float4*)(o + 4 * j) = v;
  }
}

// filt/gate: [d][r*2+tap] -> [d][tap*64+r], split hi/lo
__global__ __launch_bounds__(256) void wn_prep_fg_k(
    const float* __restrict__ filt, const float* __restrict__ gate,
    unsigned short* __restrict__ fH, unsigned short* __restrict__ fL,
    unsigned short* __restrict__ gH, unsigned short* __restrict__ gL) {
  int id = blockIdx.x * 256 + threadIdx.x;  // 30*64*64
  int r = id & 63, d = (id >> 6) & 63, i = id >> 12;
  size_t sb = (size_t)i * 8192 + d * 128;
  unsigned short h, l;
#pragma unroll
  for (int tap = 0; tap < 2; ++tap) {
    size_t di = sb + tap * 64 + r;
    fsplit(filt[sb + r * 2 + tap], h, l); fH[di] = h; fL[di] = l;
    fsplit(gate[sb + r * 2 + tap], h, l); gH[di] = h; gL[di] = l;
  }
}

__global__ __launch_bounds__(256) void wn_split_k(
    const float* __restrict__ src, unsigned short* __restrict__ dH,
    unsigned short* __restrict__ dL) {
  int id = blockIdx.x * 256 + threadIdx.x;
  unsigned short h, l;
  fsplit(src[id], h, l);
  dH[id] = h; dL[id] = l;
}

// ---------------- layer kernel (chunk-local) ----------------
// Xs row stride 260 shorts (130 words ≡ 2 mod 32 → 2-way banks, free).
// k layout: hi: tap0 r[0..64) , tap1 r[64..128); lo at +128.
__global__ __launch_bounds__(256, 2) void wn_layer_k(
    const float* __restrict__ xin, float* __restrict__ xout,
    unsigned short* __restrict__ outp,  // [NB][tc][64] bf16 (this layer, this chunk)
    const unsigned short* __restrict__ fH, const unsigned short* __restrict__ fL,
    const unsigned short* __restrict__ gH, const unsigned short* __restrict__ gL,
    const unsigned short* __restrict__ rH, const unsigned short* __restrict__ rL,
    int dil, int ti_start, int lo, int cext, int tc) {
  __shared__ unsigned short Xs[64 * 260];
  __shared__ unsigned short Os[64 * 132];  // [t][d hi 0..64, lo 64..128]

  const int tid = threadIdx.x;
  const int lane = tid & 63, wave = tid >> 6;
  const int q = lane >> 5, ln = lane & 31;
  const int b = blockIdx.y;
  const int ti0 = ti_start + (int)blockIdx.x * 64;
  const float* xb = xin + (size_t)b * cext * 64;

  // ---- stage X tile ----
  {
    int row = tid >> 2, cg = (tid & 3) << 4;
    const float* src = xb + (size_t)(ti0 + row) * 64 + cg;
    unsigned short* dh = &Xs[row * 260 + 64 + cg];
    unsigned short* dl = &Xs[row * 260 + 192 + cg];
#pragma unroll
    for (int j = 0; j < 4; ++j) {
      float4 v = *(const float4*)(src + 4 * j);
      uint2 h, l; split4(v, h, l);
      *(uint2*)(dh + 4 * j) = h; *(uint2*)(dl + 4 * j) = l;
    }
    int ts = ti0 + row - dil;
    dh = &Xs[row * 260 + cg];
    dl = &Xs[row * 260 + 128 + cg];
    if (ts >= 0) {
      const float* s2 = xb + (size_t)ts * 64 + cg;
#pragma unroll
      for (int j = 0; j < 4; ++j) {
        float4 v = *(const float4*)(s2 + 4 * j);
        uint2 h, l; split4(v, h, l);
        *(uint2*)(dh + 4 * j) = h; *(uint2*)(dl + 4 * j) = l;
      }
    } else {
      uint2 z; z.x = 0; z.y = 0;
#pragma unroll
      for (int j = 0; j < 4; ++j) { *(uint2*)(dh + 4 * j) = z; *(uint2*)(dl + 4 * j) = z; }
    }
  }

  const int dblk = wave >> 1, tblk = wave & 1;
  const int arow = dblk * 32 + ln;

  // conv A-frags register-resident
  uint4 afh[8], afl[8], agh[8], agl[8];
  {
    const uint4* pfh = (const uint4*)fH;
    const uint4* pfl = (const uint4*)fL;
    const uint4* pgh = (const uint4*)gH;
    const uint4* pgl = (const uint4*)gL;
#pragma unroll
    for (int kc = 0; kc < 8; ++kc) {
      int ai = arow * 16 + kc * 2 + q;
      afh[kc] = pfh[ai]; afl[kc] = pfl[ai];
      agh[kc] = pgh[ai]; agl[kc] = pgl[ai];
    }
  }
  __syncthreads();

  f32x16 accF, accG;
#pragma unroll
  for (int i = 0; i < 16; ++i) { accF[i] = 0.f; accG[i] = 0.f; }

  const unsigned short* xrow = &Xs[(tblk * 32 + ln) * 260];
#pragma unroll
  for (int kc = 0; kc < 8; ++kc) {
    uint2 h0 = *(const uint2*)(xrow + kc * 16 + q * 8);
    uint2 h1 = *(const uint2*)(xrow + kc * 16 + q * 8 + 4);
    uint2 l0 = *(const uint2*)(xrow + 128 + kc * 16 + q * 8);
    uint2 l1 = *(const uint2*)(xrow + 128 + kc * 16 + q * 8 + 4);
    bf16x8 bh = asb2(h0, h1), bl = asb2(l0, l1);
    accF = MFMA32(asb(afh[kc]), bh, accF);
    accF = MFMA32(asb(afh[kc]), bl, accF);
    accF = MFMA32(asb(afl[kc]), bh, accF);
    accG = MFMA32(asb(agh[kc]), bh, accG);
    accG = MFMA32(asb(agh[kc]), bl, accG);
    accG = MFMA32(asb(agl[kc]), bh, accG);
  }

  // ---- activation -> Os (hi/lo) + global outs (bf16 hi) ----
  {
    int trow = tblk * 32 + ln;
    unsigned short* orow = &Os[trow * 132 + dblk * 32];
    bool wout = (ti0 >= lo);
    unsigned short* gout = outp + ((size_t)b * tc + (ti0 - lo + trow)) * 64 + dblk * 32;
#pragma unroll
    for (int g = 0; g < 4; ++g) {
      int dofs = 8 * g + 4 * q;
      unsigned short oh[4], ol[4];
#pragma unroll
      for (int j = 0; j < 4; ++j) {
        float f = fast_tanh(accF[g * 4 + j]) * fast_sigmoid(accG[g * 4 + j]);
        fsplit(f, oh[j], ol[j]);
      }
      uint2 hv, lv;
      hv.x = (unsigned int)oh[0] | ((unsigned int)oh[1] << 16);
      hv.y = (unsigned int)oh[2] | ((unsigned int)oh[3] << 16);
      lv.x = (unsigned int)ol[0] | ((unsigned int)ol[1] << 16);
      lv.y = (unsigned int)ol[2] | ((unsigned int)ol[3] << 16);
      *(uint2*)(orow + dofs) = hv;
      *(uint2*)(orow + 64 + dofs) = lv;
      if (wout) *(uint2*)(gout + dofs) = hv;
    }
  }
  __syncthreads();

  // ---- residual: xout = x + res_w @ out ----
  {
    const int rblk = wave >> 1, tb2 = wave & 1;
    uint4 arh[4], arl[4];
    const uint4* prh = (const uint4*)rH;
    const uint4* prl = (const uint4*)rL;
#pragma unroll
    for (int kc = 0; kc < 4; ++kc) {
      int ai = (rblk * 32 + ln) * 8 + kc * 2 + q;
      arh[kc] = prh[ai]; arl[kc] = prl[ai];
    }
    f32x16 accR;
#pragma unroll
    for (int i = 0; i < 16; ++i) accR[i] = 0.f;
    const int t = tb2 * 32 + ln;
    const unsigned short* orow = &Os[t * 132];
#pragma unroll
    for (int kc = 0; kc < 4; ++kc) {
      uint2 h0 = *(const uint2*)(orow + kc * 16 + q * 8);
      uint2 h1 = *(const uint2*)(orow + kc * 16 + q * 8 + 4);
      uint2 l0 = *(const uint2*)(orow + 64 + kc * 16 + q * 8);
      uint2 l1 = *(const uint2*)(orow + 64 + kc * 16 + q * 8 + 4);
      bf16x8 bh = asb2(h0, h1), bl = asb2(l0, l1);
      accR = MFMA32(asb(arh[kc]), bh, accR);
      accR = MFMA32(asb(arh[kc]), bl, accR);
      accR = MFMA32(asb(arl[kc]), bh, accR);
    }
    float* xo = xout + ((size_t)b * cext + ti0 + t) * 64;
#pragma unroll
    for (int g = 0; g < 4; ++g) {
      int rbase = rblk * 32 + 8 * g + 4 * q;
      uint2 xh = *(const uint2*)&Xs[t * 260 + 64 + rbase];
      uint2 xl = *(const uint2*)&Xs[t * 260 + 192 + rbase];
      float4 v;
      v.x = accR[g * 4 + 0] + bflo(xh.x) + bflo(xl.x);
      v.y = accR[g * 4 + 1] + bfhi2(xh.x) + bfhi2(xl.x);
      v.z = accR[g * 4 + 2] + bflo(xh.y) + bflo(xl.y);
      v.w = accR[g * 4 + 3] + bfhi2(xh.y) + bfhi2(xl.y);
      *(float4*)(xo + rbase) = v;
    }
  }
}

// ---------------- fused skip-sum + head (per chunk) ----------------
// Skip loop double-buffered: global loads for layer i+1 issued into registers
// before layer i's MFMAs; written to the alternate LDS buffer after compute.
__global__ __launch_bounds__(256, 3) void wn_skipend_k(
    const unsigned short* __restrict__ outs,  // [30][NB][tc][64]
    const unsigned short* __restrict__ sH, const unsigned short* __restrict__ sL,
    const unsigned short* __restrict__ e1H, const unsigned short* __restrict__ e1L,
    const float* __restrict__ b1,
    const unsigned short* __restrict__ e2H, const unsigned short* __restrict__ e2L,
    const float* __restrict__ b2, float* __restrict__ out, int c0, int tc) {
  __shared__ unsigned short SM[64 * 260];  // 2x (64x68) during skip; Hs (64x260) after

  const int tid = threadIdx.x;
  const int lane = tid & 63, wave = tid >> 6;
  const int q = lane >> 5, ln = lane & 31;
  const int b = blockIdx.y;
  const int tl0 = (int)blockIdx.x * 64;

  f32x16 acc[4];  // [sblk][tt]
#pragma unroll
  for (int a = 0; a < 4; ++a)
#pragma unroll
    for (int i = 0; i < 16; ++i) acc[a][i] = 0.f;

  // staging decomposition: each thread owns 2x uint4 (32 B) of the 8 KB tile
  const int r0 = tid >> 3, c80 = (tid & 7) << 3;  // rows 0..31
  const int r1 = r0 + 32;                          // rows 32..63

  uint4 ld0, ld1;
  {
    const unsigned short* src = outs + ((size_t)b * tc + tl0) * 64;  // layer 0
    ld0 = *(const uint4*)(src + r0 * 64 + c80);
    ld1 = *(const uint4*)(src + r1 * 64 + c80);
  }
  int cur = 0;
  {  // write buf0
    unsigned short* base = SM;
    uint2 a0; a0.x = ld0.x; a0.y = ld0.y;
    uint2 a1; a1.x = ld0.z; a1.y = ld0.w;
    *(uint2*)&base[r0 * 68 + c80] = a0;
    *(uint2*)&base[r0 * 68 + c80 + 4] = a1;
    uint2 b0; b0.x = ld1.x; b0.y = ld1.y;
    uint2 b1v; b1v.x = ld1.z; b1v.y = ld1.w;
    *(uint2*)&base[r1 * 68 + c80] = b0;
    *(uint2*)&base[r1 * 68 + c80 + 4] = b1v;
  }

  for (int i = 0; i < NLAYER; ++i) {
    if (i + 1 < NLAYER) {  // issue next layer's loads early (overlap with MFMA)
      const unsigned short* src = outs + (((size_t)(i + 1) * NB + b) * tc + tl0) * 64;
      ld0 = *(const uint4*)(src + r0 * 64 + c80);
      ld1 = *(const uint4*)(src + r1 * 64 + c80);
    }
    __syncthreads();  // buf[cur] writes visible to all
    const unsigned short* sbuf = SM + cur * (64 * 68);
    const uint4* pa = (const uint4*)sH + (size_t)i * 2048;
    const uint4* pl = (const uint4*)sL + (size_t)i * 2048;
#pragma unroll 2
    for (int kc = 0; kc < 4; ++kc) {
#pragma unroll
      for (int sblk = 0; sblk < 2; ++sblk) {
        uint4 ah = pa[(wave * 64 + sblk * 32 + ln) * 8 + kc * 2 + q];
        uint4 al = pl[(wave * 64 + sblk * 32 + ln) * 8 + kc * 2 + q];
#pragma unroll
        for (int tt = 0; tt < 2; ++tt) {
          uint2 b0 = *(const uint2*)&sbuf[(tt * 32 + ln) * 68 + kc * 16 + q * 8];
          uint2 b1v = *(const uint2*)&sbuf[(tt * 32 + ln) * 68 + kc * 16 + q * 8 + 4];
          bf16x8 bb = asb2(b0, b1v);
          acc[sblk * 2 + tt] = MFMA32(asb(ah), bb, acc[sblk * 2 + tt]);
          acc[sblk * 2 + tt] = MFMA32(asb(al), bb, acc[sblk * 2 + tt]);
        }
      }
    }
    if (i + 1 < NLAYER) {  // write next layer into the other buffer
      unsigned short* base = SM + (cur ^ 1) * (64 * 68);
      uint2 a0; a0.x = ld0.x; a0.y = ld0.y;
      uint2 a1; a1.x = ld0.z; a1.y = ld0.w;
      *(uint2*)&base[r0 * 68 + c80] = a0;
      *(uint2*)&base[r0 * 68 + c80 + 4] = a1;
      uint2 b0; b0.x = ld1.x; b0.y = ld1.y;
      uint2 b1v; b1v.x = ld1.z; b1v.y = ld1.w;
      *(uint2*)&base[r1 * 68 + c80] = b0;
      *(uint2*)&base[r1 * 68 + c80 + 4] = b1v;
    }
    cur ^= 1;
  }
  __syncthreads();
  // h = relu(skip) -> Hs bf16 (row stride 260)
#pragma unroll
  for (int sblk = 0; sblk < 2; ++sblk)
#pragma unroll
    for (int tt = 0; tt < 2; ++tt) {
      int t = tt * 32 + ln;
#pragma unroll
      for (int g = 0; g < 4; ++g) {
        int s = wave * 64 + sblk * 32 + 8 * g + 4 * q;
        unsigned short h0 = bfh(fmaxf(acc[sblk * 2 + tt][g * 4 + 0], 0.f));
        unsigned short h1 = bfh(fmaxf(acc[sblk * 2 + tt][g * 4 + 1], 0.f));
        unsigned short h2 = bfh(fmaxf(acc[sblk * 2 + tt][g * 4 + 2], 0.f));
        unsigned short h3 = bfh(fmaxf(acc[sblk * 2 + tt][g * 4 + 3], 0.f));
        uint2 hv;
        hv.x = (unsigned int)h0 | ((unsigned int)h1 << 16);
        hv.y = (unsigned int)h2 | ((unsigned int)h3 << 16);
        *(uint2*)&SM[t * 260 + s] = hv;
      }
    }
  __syncthreads();

  // e1: acc = e1 @ h  (2-term weights)
#pragma unroll
  for (int a = 0; a < 4; ++a)
#pragma unroll
    for (int i = 0; i < 16; ++i) acc[a][i] = 0.f;
  const uint4* p1h = (const uint4*)e1H;
  const uint4* p1l = (const uint4*)e1L;
#pragma unroll 4
  for (int kc = 0; kc < 16; ++kc) {
#pragma unroll
    for (int ot = 0; ot < 2; ++ot) {
      uint4 ah = p1h[(wave * 64 + ot * 32 + ln) * 32 + kc * 2 + q];
      uint4 al = p1l[(wave * 64 + ot * 32 + ln) * 32 + kc * 2 + q];
#pragma unroll
      for (int tt = 0; tt < 2; ++tt) {
        uint2 b0 = *(const uint2*)&SM[(tt * 32 + ln) * 260 + kc * 16 + q * 8];
        uint2 b1v = *(const uint2*)&SM[(tt * 32 + ln) * 260 + kc * 16 + q * 8 + 4];
        bf16x8 bb = asb2(b0, b1v);
        acc[ot * 2 + tt] = MFMA32(asb(ah), bb, acc[ot * 2 + tt]);
        acc[ot * 2 + tt] = MFMA32(asb(al), bb, acc[ot * 2 + tt]);
      }
    }
  }
  __syncthreads();
  // h2 = relu(acc + b1) -> Hs
#pragma unroll
  for (int ot = 0; ot < 2; ++ot)
#pragma unroll
    for (int tt = 0; tt < 2; ++tt) {
      int t = tt * 32 + ln;
#pragma unroll
      for (int g = 0; g < 4; ++g) {
        int o = wave * 64 + ot * 32 + 8 * g + 4 * q;
        float4 bb = *(const float4*)(b1 + o);
        unsigned short h0 = bfh(fmaxf(acc[ot * 2 + tt][g * 4 + 0] + bb.x, 0.f));
        unsigned short h1 = bfh(fmaxf(acc[ot * 2 + tt][g * 4 + 1] + bb.y, 0.f));
        unsigned short h2 = bfh(fmaxf(acc[ot * 2 + tt][g * 4 + 2] + bb.z, 0.f));
        unsigned short h3 = bfh(fmaxf(acc[ot * 2 + tt][g * 4 + 3] + bb.w, 0.f));
        uint2 hv;
        hv.x = (unsigned int)h0 | ((unsigned int)h1 << 16);
        hv.y = (unsigned int)h2 | ((unsigned int)h3 << 16);
        *(uint2*)&SM[t * 260 + o] = hv;
      }
    }
  __syncthreads();

  // e2: acc = e2 @ h2
#pragma unroll
  for (int a = 0; a < 4; ++a)
#pragma unroll
    for (int i = 0; i < 16; ++i) acc[a][i] = 0.f;
  const uint4* p2h = (const uint4*)e2H;
  const uint4* p2l = (const uint4*)e2L;
#pragma unroll 4
  for (int kc = 0; kc < 16; ++kc) {
#pragma unroll
    for (int ot = 0; ot < 2; ++ot) {
      uint4 ah = p2h[(wave * 64 + ot * 32 + ln) * 32 + kc * 2 + q];
      uint4 al = p2l[(wave * 64 + ot * 32 + ln) * 32 + kc * 2 + q];
#pragma unroll
      for (int tt = 0; tt < 2; ++tt) {
        uint2 b0 = *(const uint2*)&SM[(tt * 32 + ln) * 260 + kc * 16 + q * 8];
        uint2 b1v = *(const uint2*)&SM[(tt * 32 + ln) * 260 + kc * 16 + q * 8 + 4];
        bf16x8 bb = asb2(b0, b1v);
        acc[ot * 2 + tt] = MFMA32(asb(ah), bb, acc[ot * 2 + tt]);
        acc[ot * 2 + tt] = MFMA32(asb(al), bb, acc[ot * 2 + tt]);
      }
    }
  }
  // final store: out[b][c0+tl0+t][c] = acc + b2
#pragma unroll
  for (int ot = 0; ot < 2; ++ot)
#pragma unroll
    for (int tt = 0; tt < 2; ++tt) {
      int t = tt * 32 + ln;
      float* op = out + ((size_t)b * TLEN + c0 + tl0 + t) * 256;
#pragma unroll
      for (int g = 0; g < 4; ++g) {
        int o = wave * 64 + ot * 32 + 8 * g + 4 * q;
        float4 bb = *(const float4*)(b2 + o);
        float4 v;
        v.x = acc[ot * 2 + tt][g * 4 + 0] + bb.x;
        v.y = acc[ot * 2 + tt][g * 4 + 1] + bb.y;
        v.z = acc[ot * 2 + tt][g * 4 + 2] + bb.z;
        v.w = acc[ot * 2 + tt][g * 4 + 3] + bb.w;
        *(float4*)(op + o) = v;
      }
    }
}

extern "C" void kernel_launch(void* const* d_in, const int* in_sizes, int n_in,
                              void* d_out, int out_size, void* d_ws,
                              size_t ws_size, hipStream_t stream) {
  (void)in_sizes; (void)n_in; (void)out_size;
  const float* y     = (const float*)d_in[0];
  const float* cw    = (const float*)d_in[1];
  const float* cb    = (const float*)d_in[2];
  const float* filt  = (const float*)d_in[3];
  const float* gate  = (const float*)d_in[4];
  const float* resw  = (const float*)d_in[5];
  const float* skipw = (const float*)d_in[6];
  const float* w1    = (const float*)d_in[7];
  const float* b1    = (const float*)d_in[8];
  const float* w2    = (const float*)d_in[9];
  const float* b2    = (const float*)d_in[10];
  float* out = (float*)d_out;

  // per-layer halo (valid-region chain), 64-aligned
  int P[NLAYER];
  P[NLAYER - 1] = 0;
  for (int i = NLAYER - 1; i >= 1; --i) {
    int d = 1 << (i % 10);
    P[i - 1] = ((P[i] + d + 63) / 64) * 64;
  }
  const int LO = ((P[0] + 1 + 63) / 64) * 64;  // = 4032 (covers full receptive field)

  // weight-split sizes (shorts)
  const size_t nFG = (size_t)NLAYER * 8192;
  const size_t nRes = (size_t)NLAYER * 4096;
  const size_t nSkip = (size_t)NLAYER * 16384;
  const size_t nE = 65536;
  const size_t wTot = 4 * nFG + 2 * nRes + 2 * nSkip + 4 * nE;  // shorts

  // adaptive chunking: fewer, bigger chunks = more blocks per launch + less
  // halo recompute. Fall back if workspace can't hold the outs buffer.
  auto need = [&](int tcv, int lov) -> size_t {
    return 2ull * NB * (size_t)(tcv + lov) * 64 * 4     // xtA + xtB (fp32)
         + (size_t)NLAYER * NB * (size_t)tcv * 64 * 2   // outs (bf16)
         + wTot * 2;                                    // weight splits
  };
  int tc, lo, nchunk;
  if (ws_size >= need(TLEN, 0)) {
    tc = TLEN; lo = 0; nchunk = 1;          // ~549 MB
  } else if (ws_size >= need(TLEN / 2, LO)) {
    tc = TLEN / 2; lo = LO; nchunk = 2;     // ~298 MB
  } else {
    tc = TLEN / 4; lo = LO; nchunk = 4;     // ~156 MB (previous layout)
  }
  const int cext = tc + lo;

  // ws carve: xtA | xtB (chunk-local fp32 x) | outs (chunk bf16) | weight splits
  const size_t NXTr = (size_t)NB * cext * 64;
  float* xtA = (float*)d_ws;
  float* xtB = xtA + NXTr;
  unsigned short* outsB = (unsigned short*)(xtB + NXTr);
  const size_t outsN = (size_t)NLAYER * NB * (size_t)tc * 64;
  unsigned short* wb = outsB + outsN;
  unsigned short* fH = wb;            unsigned short* fL = fH + nFG;
  unsigned short* gH = fL + nFG;      unsigned short* gL = gH + nFG;
  unsigned short* rH = gL + nFG;      unsigned short* rL = rH + nRes;
  unsigned short* sH = rL + nRes;     unsigned short* sL = sH + nSkip;
  unsigned short* e1H = sL + nSkip;   unsigned short* e1L = e1H + nE;
  unsigned short* e2H = e1L + nE;     unsigned short* e2L = e2H + nE;

  wn_prep_fg_k<<<dim3(NLAYER * 64 * 64 / 256), dim3(256), 0, stream>>>(
      filt, gate, fH, fL, gH, gL);
  wn_split_k<<<dim3(nRes / 256), dim3(256), 0, stream>>>(resw, rH, rL);
  wn_split_k<<<dim3(nSkip / 256), dim3(256), 0, stream>>>(skipw, sH, sL);
  wn_split_k<<<dim3(nE / 256), dim3(256), 0, stream>>>(w1, e1H, e1L);
  wn_split_k<<<dim3(nE / 256), dim3(256), 0, stream>>>(w2, e2H, e2L);

  for (int c = 0; c < nchunk; ++c) {
    int c0 = c * tc;
    int loc = (c == 0) ? 0 : lo;
    int ext = tc + loc;
    int base = c0 - loc;
    wn_causal_k<<<dim3(ext / 64, NB), dim3(256), 0, stream>>>(y, cw, cb, xtA, base, cext);
    float* xi = xtA;
    float* xo = xtB;
    for (int i = 0; i < NLAYER; ++i) {
      int d = 1 << (i % 10);
      int Pe = (c == 0) ? 0 : P[i];
      int nt = tc + Pe;
      wn_layer_k<<<dim3(nt / 64, NB), dim3(256), 0, stream>>>(
          xi, xo, outsB + (size_t)i * NB * (size_t)tc * 64,
          fH + (size_t)i * 8192, fL + (size_t)i * 8192,
          gH + (size_t)i * 8192, gL + (size_t)i * 8192,
          rH + (size_t)i * 4096, rL + (size_t)i * 4096,
          d, loc - Pe, loc, cext, tc);
      float* tmp = xi; xi = xo; xo = tmp;
    }
    wn_skipend_k<<<dim3(tc / 64, NB), dim3(256), 0, stream>>>(
        outsB, sH, sL, e1H, e1L, b1, e2H, e2L, b2, out, c0, tc);
  }
}